// Round 10
// baseline (412.665 us; speedup 1.0000x reference)
//
#include <hip/hip_runtime.h>
#include <hip/hip_bf16.h>
#include <stdint.h>

// Problem constants
#define B_N   2048
#define XW    128      // x row width (real 64 | meta 64)
#define KDIM  512      // W_out column count (= H)
#define NROWS_W   66112
#define NROWS_PAD 66560   // padded bf16-W rows

typedef __bf16 v8bf  __attribute__((ext_vector_type(8)));
typedef float  f32x4 __attribute__((ext_vector_type(4)));

__device__ __forceinline__ unsigned short f2bf(float f) {
    uint32_t u = __float_as_uint(f);
    u += 0x7FFF + ((u >> 16) & 1);          // round-to-nearest-even
    return (unsigned short)(u >> 16);
}
__device__ __forceinline__ float elu1(float v) {
    return v > 0.0f ? v : expm1f(v);
}
__device__ __forceinline__ void gload_lds16(const void* g, void* l) {
    __builtin_amdgcn_global_load_lds(
        (const __attribute__((address_space(1))) unsigned int*)g,
        (__attribute__((address_space(3))) unsigned int*)l, 16, 0, 0);
}

// ---------------- K1: h = elu(meta @ W_in^T + b_in), stored bf16 ----------------
__global__ void k_h(const float* __restrict__ x, const float* __restrict__ W_in,
                    const float* __restrict__ b_in, unsigned short* __restrict__ hb) {
    int idx = blockIdx.x * 256 + threadIdx.x;      // b*512 + j
    int b = idx >> 9, j = idx & 511;
    const float4* xm = (const float4*)(x + (size_t)b * XW + 64);
    const float4* wr = (const float4*)(W_in + (size_t)j * 64);
    float acc = 0.f;
#pragma unroll
    for (int q = 0; q < 16; ++q) {
        float4 a = xm[q], w = wr[q];
        acc += a.x * w.x + a.y * w.y + a.z * w.z + a.w * w.w;
    }
    acc = elu1(acc + b_in[j]);
    hb[idx] = f2bf(acc);
}

// ---------------- K-conv: W_out f32 -> bf16 (padded rows zeroed) ---------------
__global__ void k_conv(const float* __restrict__ Wf, unsigned short* __restrict__ Wb) {
    size_t c = (size_t)blockIdx.x * 256 + threadIdx.x;  // 8-elem chunk id
    size_t row = c >> 6; int kk = (int)(c & 63);
    union { uint4 v; unsigned short u[8]; } o;
    o.v = (uint4){0, 0, 0, 0};
    if (row < NROWS_W) {
        const float* wp = Wf + row * KDIM + kk * 8;
        float4 w0 = *(const float4*)wp, w1 = *(const float4*)(wp + 4);
        o.u[0] = f2bf(w0.x); o.u[1] = f2bf(w0.y); o.u[2] = f2bf(w0.z); o.u[3] = f2bf(w0.w);
        o.u[4] = f2bf(w1.x); o.u[5] = f2bf(w1.y); o.u[6] = f2bf(w1.z); o.u[7] = f2bf(w1.w);
    }
    *(uint4*)(Wb + c * 8) = o.v;
}

// ---------------- K-init-ypre: ypre = b_out[32768+hh] + sum_i real_i*b_out[i*512+hh]
__global__ void k_init_ypre(const float* __restrict__ x, const float* __restrict__ b_out,
                            float* __restrict__ ypre) {
    int idx = blockIdx.x * 256 + threadIdx.x;   // b*512 + hh
    int b = idx >> 9, hh = idx & 511;
    float acc = b_out[32768 + hh];
    const float* xr = x + (size_t)b * XW;       // real part
#pragma unroll 8
    for (int i = 0; i < 64; ++i)
        acc += xr[i] * b_out[i * 512 + hh];
    ypre[idx] = acc;
}

// ---------------- K-y: yv = elu(ypre) ------------------------------------------
__global__ void k_y(const float* __restrict__ ypre, float* __restrict__ yv) {
    int idx = blockIdx.x * 256 + threadIdx.x;
    yv[idx] = elu1(ypre[idx]);
}

// ---------------- K-init-out: out = b_out[66048+o] + sum_hh yv*b_out[33280+hh*64+o]
__global__ void k_init_out(const float* __restrict__ yv, const float* __restrict__ b_out,
                           float* __restrict__ out) {
    int idx = blockIdx.x * 256 + threadIdx.x;   // b*64 + o
    int b = idx >> 6, o = idx & 63;
    float acc = b_out[66048 + o];
    const float* yr = yv + (size_t)b * 512;
#pragma unroll 4
    for (int hh = 0; hh < 512; ++hh)
        acc += yr[hh] * b_out[33280 + hh * 64 + o];
    out[idx] = acc;
}

// ---------------- panel GEMM: BM=256, A-in-regs, ring-4 depth-3 ----------------
// P[b,c] = sum_k h[b,k] * W[panelrow(p)+c, k]   (bf16 MFMA, K-quarters of 128)
// outAcc[b, outcol] += s(b, grp) * P            (f32 fold per phase, linear in K)
// Block: 256 rows x 128 panel-cols, 512 thr (8 waves 4M x 2N, wave-tile 64x64).
// 32 splits x {4,5} panels. B ring: 4 x 16KB LDS, stage t+3 at phase t,
// steady s_waitcnt vmcnt(6) (stage = 2 gload_lds). A (=h) frags in regs per kq.
// B-traffic = 8 M-tiles x 34MB = 272MB (half of R6's 545MB) -> BW-hypothesis test.
template<int MODE>
__global__ __launch_bounds__(512, 2)
void k_pgemm(const unsigned short* __restrict__ hb,
             const unsigned short* __restrict__ Wb,
             const float* __restrict__ scaleSrc,
             float* __restrict__ outAcc) {
    constexpr int NP   = MODE ? 129 : 130;
    constexpr int OUTW = MODE ? 64 : 512;
    constexpr int SCW  = MODE ? 10 : 5;

    __shared__ char smem[65536 + SCW * 256 * 4];
    char* Bs = smem;                         // 4 x [128 rows][128B] ring, swizzled
    float* sc = (float*)(smem + 65536);      // [SCW][256]

    // Decode: 8 M-tiles per group; group's 8 blocks share lid%8 -> one XCD.
    const int lid = blockIdx.x;              // [0,512)
    const int c8 = lid & 7, qq = lid >> 3;
    const int mtile = qq & 7, ghi = qq >> 3;
    const int grp = ghi * 8 + c8;            // 0..63
    const int s  = grp >> 1, nh = grp & 1;   // split 0..31, N-half
    const int m0 = mtile * 256;

    const int pBeg = (NP * s) >> 5;
    const int pEnd = (NP * (s + 1)) >> 5;
    const int NPAN = pEnd - pBeg;            // 4 or 5
    const int halfS = (MODE == 0 && pBeg >= 65) ? 1 : 0;   // uniform per split
    const int iBeg  = pBeg - halfS * 65;

    const int tid = threadIdx.x;
    const int wid = tid >> 6, l = tid & 63;
    const int lr = l & 15, lg = l >> 4;
    const int wm = wid >> 1, wn = wid & 1;   // wave grid 4M x 2N

    // ---- stage scales (f32) ----
    for (int c = tid; c < SCW * 256; c += 512) {
        int jj = c >> 8, row = c & 255;
        float v = 1.0f;
        if (MODE == 0) {
            int i = iBeg + jj;
            if (i < 64) v = scaleSrc[(size_t)(m0 + row) * XW + i];
        } else {
            int gg = (pBeg + (jj >> 1)) * 4 + nh * 2 + (jj & 1);
            if (gg < 512) v = scaleSrc[(size_t)(m0 + row) * KDIM + gg];  // yv (elu'd)
        }
        sc[c] = v;
    }
    __syncthreads();

    int bRow[4];
#pragma unroll
    for (int q = 0; q < 4; ++q) bRow[q] = wn * 64 + q * 16 + lr;

    f32x4 accO[4][4];
#pragma unroll
    for (int mi = 0; mi < 4; ++mi)
#pragma unroll
        for (int ni = 0; ni < 4; ++ni) accO[mi][ni] = (f32x4){0.f, 0.f, 0.f, 0.f};

    const int r0 = tid >> 3;                        // 0..63 (staging row)
    const int k8 = ((tid & 7) ^ (r0 & 7)) * 8;      // inverse read-swizzle (elems)

    for (int kq = 0; kq < 4; ++kq) {
        // ---- A frags for this kq -> regs (L2-hot); all indices static ----
        const unsigned short* ab = hb + (size_t)(m0 + wm * 64 + lr) * KDIM
                                 + kq * 128 + lg * 8;
        v8bf areg[4][4];                            // [mi][ks 0..3]
#pragma unroll
        for (int mi = 0; mi < 4; ++mi)
#pragma unroll
            for (int ks = 0; ks < 4; ++ks)
                areg[mi][ks] = *(const v8bf*)(ab + mi * 16 * KDIM + ks * 32);

        auto stageB = [&](int slotB, int pp2, int k0c) {
            const int wrowB = MODE ? (33280 + (pBeg + pp2) * 256 + nh * 128)
                                   : ((iBeg + pp2) * 512 + halfS * 256 + nh * 128);
            const unsigned short* src = Wb + (size_t)(wrowB + r0) * KDIM
                                      + kq * 128 + k0c * 64 + k8;
            char* dst = Bs + slotB * 16384 + tid * 16;
            gload_lds16(src, dst);                        // rows 0..63
            gload_lds16(src + (size_t)64 * KDIM, dst + 8192);  // rows 64..127
        };

        const int NPH = 2 * NPAN;                   // 8 or 10
        stageB(0, 0, 0); stageB(1, 0, 1); stageB(2, 1, 0);
        int slot = 0;

        for (int pp = 0; pp < NPAN; ++pp) {
            f32x4 sv[4];
#pragma unroll
            for (int k0 = 0; k0 < 2; ++k0) {        // static k0 (rule #20)
                const int t = pp * 2 + k0;
                if (t + 3 < NPH) {
                    int ns = slot + 3; if (ns >= 4) ns -= 4;
                    const int t3 = t + 3;
                    stageB(ns, t3 >> 1, t3 & 1);
                    asm volatile("s_waitcnt vmcnt(6)" ::: "memory");
                } else if (t + 2 < NPH) {
                    asm volatile("s_waitcnt vmcnt(4)" ::: "memory");
                } else if (t + 1 < NPH) {
                    asm volatile("s_waitcnt vmcnt(2)" ::: "memory");
                } else {
                    asm volatile("s_waitcnt vmcnt(0)" ::: "memory");
                }
                __builtin_amdgcn_s_barrier();       // slot ready for all waves
                asm volatile("" ::: "memory");
                const char* Bbuf = Bs + slot * 16384;
                if (k0 == 0) {                      // sv reused at k0==1
                    const int jj = MODE ? (pp * 2 + wn) : pp;
                    const float* scp = sc + jj * 256 + wm * 64 + lg * 4;
#pragma unroll
                    for (int mi = 0; mi < 4; ++mi)
                        sv[mi] = *(const f32x4*)(scp + mi * 16);
                }
                v8bf bfr[4][2];
#pragma unroll
                for (int ni = 0; ni < 4; ++ni)
#pragma unroll
                    for (int ks = 0; ks < 2; ++ks)
                        bfr[ni][ks] = *(const v8bf*)(Bbuf + bRow[ni] * 128
                                      + (((ks * 4 + lg) ^ (bRow[ni] & 7)) << 4));
                __builtin_amdgcn_s_setprio(1);
#pragma unroll
                for (int mi = 0; mi < 4; ++mi) {
#pragma unroll
                    for (int ni = 0; ni < 4; ++ni) {
                        f32x4 t0 = __builtin_amdgcn_mfma_f32_16x16x32_bf16(
                            areg[mi][k0 * 2], bfr[ni][0],
                            (f32x4){0.f, 0.f, 0.f, 0.f}, 0, 0, 0);
                        t0 = __builtin_amdgcn_mfma_f32_16x16x32_bf16(
                            areg[mi][k0 * 2 + 1], bfr[ni][1], t0, 0, 0, 0);
                        accO[mi][ni] += sv[mi] * t0;   // fold (linear in K)
                    }
                }
                __builtin_amdgcn_s_setprio(0);
                asm volatile("" ::: "memory");
                __builtin_amdgcn_s_barrier();       // reads done: slot reusable
                slot = (slot == 3) ? 0 : slot + 1;
            }
        }
    }
    // ---- epilogue: atomic accumulate ----
#pragma unroll
    for (int mi = 0; mi < 4; ++mi)
#pragma unroll
        for (int ni = 0; ni < 4; ++ni)
#pragma unroll
            for (int r = 0; r < 4; ++r) {
                int row = m0 + wm * 64 + mi * 16 + lg * 4 + r;
                int col = MODE ? (ni * 16 + lr)
                               : (halfS * 256 + nh * 128 + wn * 64 + ni * 16 + lr);
                atomicAdd(outAcc + (size_t)row * OUTW + col, accO[mi][ni][r]);
            }
}

extern "C" void kernel_launch(void* const* d_in, const int* in_sizes, int n_in,
                              void* d_out, int out_size, void* d_ws, size_t ws_size,
                              hipStream_t stream) {
    const float* x     = (const float*)d_in[0];
    const float* W_in  = (const float*)d_in[1];
    const float* b_in  = (const float*)d_in[2];
    const float* W_out = (const float*)d_in[3];
    const float* b_out = (const float*)d_in[4];
    float* out = (float*)d_out;

    char* ws = (char*)d_ws;
    unsigned short* hb = (unsigned short*)ws;            // 2 MB  h bf16
    float* ypre        = (float*)(ws + (2u << 20));      // 4 MB
    float* yv          = (float*)(ws + (6u << 20));      // 4 MB  yv = elu(ypre)
    unsigned short* Wb = (unsigned short*)(ws + (10u << 20));  // 68.2 MB bf16 W_out

    k_h<<<(B_N * 512) / 256, 256, 0, stream>>>(x, W_in, b_in, hb);
    k_conv<<<((size_t)NROWS_PAD * KDIM / 8) / 256, 256, 0, stream>>>(W_out, Wb);

    // ypre := bias terms (l_in_b bias + real-weighted l_in_w biases)
    k_init_ypre<<<(B_N * 512) / 256, 256, 0, stream>>>(x, b_out, ypre);

    // Stage 2: ypre += sum_i real_i * (h @ W_i^T)
    k_pgemm<0><<<512, 512, 0, stream>>>(hb, Wb, x, ypre);

    // yv := elu(ypre)
    k_y<<<(B_N * 512) / 256, 256, 0, stream>>>(ypre, yv);

    // out := bias terms (l_out_b bias + yv-weighted l_out_w biases)
    k_init_out<<<(B_N * 64) / 256, 256, 0, stream>>>(yv, b_out, out);

    // Stage 3: out += sum_h' yv_h' * (h @ W2_h'^T)
    k_pgemm<1><<<512, 512, 0, stream>>>(hb, Wb, yv, out);
}

// Round 11
// 313.413 us; speedup vs baseline: 1.3167x; 1.3167x over previous
//
#include <hip/hip_runtime.h>
#include <hip/hip_bf16.h>
#include <stdint.h>

// Problem constants
#define B_N   2048
#define XW    128      // x row width (real 64 | meta 64)
#define KDIM  512      // W_out column count (= H)
#define NROWS_W   66112
#define NROWS_PAD 66560   // padded bf16-W rows

typedef __bf16 v8bf  __attribute__((ext_vector_type(8)));
typedef float  f32x4 __attribute__((ext_vector_type(4)));

__device__ __forceinline__ unsigned short f2bf(float f) {
    uint32_t u = __float_as_uint(f);
    u += 0x7FFF + ((u >> 16) & 1);          // round-to-nearest-even
    return (unsigned short)(u >> 16);
}
__device__ __forceinline__ float elu1(float v) {
    return v > 0.0f ? v : expm1f(v);
}
__device__ __forceinline__ void gload_lds16(const void* g, void* l) {
    __builtin_amdgcn_global_load_lds(
        (const __attribute__((address_space(1))) unsigned int*)g,
        (__attribute__((address_space(3))) unsigned int*)l, 16, 0, 0);
}

// ---------------- K1: h = elu(meta @ W_in^T + b_in), stored bf16 ----------------
__global__ void k_h(const float* __restrict__ x, const float* __restrict__ W_in,
                    const float* __restrict__ b_in, unsigned short* __restrict__ hb) {
    int idx = blockIdx.x * 256 + threadIdx.x;      // b*512 + j
    int b = idx >> 9, j = idx & 511;
    const float4* xm = (const float4*)(x + (size_t)b * XW + 64);
    const float4* wr = (const float4*)(W_in + (size_t)j * 64);
    float acc = 0.f;
#pragma unroll
    for (int q = 0; q < 16; ++q) {
        float4 a = xm[q], w = wr[q];
        acc += a.x * w.x + a.y * w.y + a.z * w.z + a.w * w.w;
    }
    acc = elu1(acc + b_in[j]);
    hb[idx] = f2bf(acc);
}

// ---------------- K-conv: W_out f32 -> bf16 (padded rows zeroed) ---------------
__global__ void k_conv(const float* __restrict__ Wf, unsigned short* __restrict__ Wb) {
    size_t c = (size_t)blockIdx.x * 256 + threadIdx.x;  // 8-elem chunk id
    size_t row = c >> 6; int kk = (int)(c & 63);
    union { uint4 v; unsigned short u[8]; } o;
    o.v = (uint4){0, 0, 0, 0};
    if (row < NROWS_W) {
        const float* wp = Wf + row * KDIM + kk * 8;
        float4 w0 = *(const float4*)wp, w1 = *(const float4*)(wp + 4);
        o.u[0] = f2bf(w0.x); o.u[1] = f2bf(w0.y); o.u[2] = f2bf(w0.z); o.u[3] = f2bf(w0.w);
        o.u[4] = f2bf(w1.x); o.u[5] = f2bf(w1.y); o.u[6] = f2bf(w1.z); o.u[7] = f2bf(w1.w);
    }
    *(uint4*)(Wb + c * 8) = o.v;
}

// ---------------- K-init-ypre: ypre = b_out[32768+hh] + sum_i real_i*b_out[i*512+hh]
__global__ void k_init_ypre(const float* __restrict__ x, const float* __restrict__ b_out,
                            float* __restrict__ ypre) {
    int idx = blockIdx.x * 256 + threadIdx.x;   // b*512 + hh
    int b = idx >> 9, hh = idx & 511;
    float acc = b_out[32768 + hh];
    const float* xr = x + (size_t)b * XW;       // real part
#pragma unroll 8
    for (int i = 0; i < 64; ++i)
        acc += xr[i] * b_out[i * 512 + hh];
    ypre[idx] = acc;
}

// ---------------- K-y: yv = elu(ypre) ------------------------------------------
__global__ void k_y(const float* __restrict__ ypre, float* __restrict__ yv) {
    int idx = blockIdx.x * 256 + threadIdx.x;
    yv[idx] = elu1(ypre[idx]);
}

// ---------------- K-init-out: out = b_out[66048+o] + sum_hh yv*b_out[33280+hh*64+o]
__global__ void k_init_out(const float* __restrict__ yv, const float* __restrict__ b_out,
                           float* __restrict__ out) {
    int idx = blockIdx.x * 256 + threadIdx.x;   // b*64 + o
    int b = idx >> 6, o = idx & 63;
    float acc = b_out[66048 + o];
    const float* yr = yv + (size_t)b * 512;
#pragma unroll 4
    for (int hh = 0; hh < 512; ++hh)
        acc += yr[hh] * b_out[33280 + hh * 64 + o];
    out[idx] = acc;
}

// ---------------- panel GEMM: BK=128 phases, ring-4, single barrier ------------
// Phase = (kq, panel): 64 MFMA/wave (4mi x 4ni x 4ks) between barriers.
// P[b,c] = sum_k h[b,k] * W[panelrow+c, k]; accP chained in AGPR from zero,
// folded into accO (VGPR) with scale once per phase.
// Block: 256 b-rows x 128 panel-cols, 512 thr, 8 waves 4M x 2N, wave 64x64.
// A (=h) frags in regs per kq. B: ring-4 x 32KB LDS, stage t+2 at phase t,
// steady s_waitcnt vmcnt(8); ONE s_barrier per phase (ring-4 makes the
// write-after-read distance 2 barriers -> safe).
// Grid 256 = 8 XCD-slots x 8 M-tiles x 4: 1 block/CU, XCD-pinned B-slices.
template<int MODE>
__global__ __launch_bounds__(512, 2)
void k_pgemm(const unsigned short* __restrict__ hb,
             const unsigned short* __restrict__ Wb,
             const float* __restrict__ scaleSrc,
             float* __restrict__ outAcc) {
    constexpr int NP     = MODE ? 257 : 65;    // panels (128 or 512 W-rows each)
    constexpr int NSPLIT = MODE ? 32 : 8;
    constexpr int OUTW   = MODE ? 64 : 512;
    constexpr int SCW    = MODE ? 18 : 9;

    __shared__ char smem[131072 + SCW * 256 * 4];
    char* Bs = smem;                         // 4 x [128 W-rows][256B] ring, swizzled
    float* sc = (float*)(smem + 131072);     // [SCW][256] f32

    // Decode: xcd = lid&7; same-xcd blocks share the split's B-slice (L2-local).
    const int lid = blockIdx.x;              // [0,256)
    const int xcd = lid & 7;
    const int mtile = (lid >> 3) & 7;
    const int chi = lid >> 6;                // 0..3
    const int combo = xcd + 8 * chi;         // 0..31
    const int s  = MODE ? combo : xcd;       // split
    const int cw = MODE ? 0 : chi;           // MODE0 col-window 0..3
    const int m0 = mtile * 256;

    const int pBeg = (NP * s) / NSPLIT;
    const int pEnd = (NP * (s + 1)) / NSPLIT;
    const int NPAN = pEnd - pBeg;            // 8 or 9
    const int NPH  = 4 * NPAN;

    const int tid = threadIdx.x;
    const int wid = tid >> 6, l = tid & 63;
    const int lr = l & 15, lg = l >> 4;
    const int wm = wid >> 1, wn = wid & 1;   // wave grid 4M x 2N

    // ---- stage scales (f32) ----
    for (int c = tid; c < SCW * 256; c += 512) {
        int jj = c >> 8, row = c & 255;
        float v = 1.0f;
        if (MODE == 0) {
            int i = pBeg + jj;
            if (i < 64) v = scaleSrc[(size_t)(m0 + row) * XW + i];
            // i == 64 -> l_in_b panel, scale 1
        } else {
            int g = pBeg * 2 + jj;
            if (g < 512) v = scaleSrc[(size_t)(m0 + row) * KDIM + g];  // yv (elu'd)
        }
        sc[c] = v;
    }
    __syncthreads();

    // staging mapping: round q: local W-row rr = q*32 + (tid>>4), 16B-slot tid&15
    const int srow   = tid >> 4;                       // 0..31
    const int schunk = ((tid & 15) ^ (srow & 7)) * 8;  // inverse read-swizzle (elems)

    int skq = 0, spp = 0;                    // next-stage coords
    auto stage = [&](int slot) {
        const int base = MODE ? (33280 + (pBeg + spp) * 128)
                              : ((pBeg + spp) * 512 + cw * 128);
        const unsigned short* s0 = Wb + (size_t)(base + srow) * KDIM
                                 + skq * 128 + schunk;
        char* d0 = Bs + slot * 32768 + tid * 16;
#pragma unroll
        for (int q = 0; q < 4; ++q)
            gload_lds16(s0 + (size_t)q * 32 * KDIM, d0 + q * 8192);
        if (++spp == NPAN) { spp = 0; ++skq; }
    };

    f32x4 accO[4][4];
#pragma unroll
    for (int mi = 0; mi < 4; ++mi)
#pragma unroll
        for (int ni = 0; ni < 4; ++ni) accO[mi][ni] = (f32x4){0.f, 0.f, 0.f, 0.f};

    stage(0); stage(1);                      // prologue: stages for t=0,1

    for (int kq = 0; kq < 4; ++kq) {
        // ---- A frags for this kq -> regs (L2-hot); all indices static ----
        const unsigned short* ab = hb + (size_t)(m0 + wm * 64 + lr) * KDIM
                                 + kq * 128 + lg * 8;
        v8bf areg[4][4];                     // [mi][ks]
#pragma unroll
        for (int mi = 0; mi < 4; ++mi)
#pragma unroll
            for (int ks = 0; ks < 4; ++ks)
                areg[mi][ks] = *(const v8bf*)(ab + mi * 16 * KDIM + ks * 32);

        for (int pp = 0; pp < NPAN; ++pp) {
            const int t = kq * NPAN + pp;
            if (t + 2 < NPH) {
                stage((t + 2) & 3);
                asm volatile("s_waitcnt vmcnt(8)" ::: "memory");  // stage(t) done
            } else if (t + 1 < NPH) {
                asm volatile("s_waitcnt vmcnt(4)" ::: "memory");
            } else {
                asm volatile("s_waitcnt vmcnt(0)" ::: "memory");
            }
            __builtin_amdgcn_s_barrier();    // the ONLY barrier per phase
            asm volatile("" ::: "memory");
            const char* Bbuf = Bs + (t & 3) * 32768;

            f32x4 accP[4][4];
            __builtin_amdgcn_s_setprio(1);
#pragma unroll
            for (int ks = 0; ks < 4; ++ks) {  // static (rule #20)
                v8bf bfr[4];
#pragma unroll
                for (int ni = 0; ni < 4; ++ni) {
                    const int brow = wn * 64 + ni * 16 + lr;
                    bfr[ni] = *(const v8bf*)(Bbuf + brow * 256
                              + (((ks * 4 + lg) ^ (brow & 7)) << 4));
                }
#pragma unroll
                for (int mi = 0; mi < 4; ++mi)
#pragma unroll
                    for (int ni = 0; ni < 4; ++ni)
                        accP[mi][ni] = __builtin_amdgcn_mfma_f32_16x16x32_bf16(
                            areg[mi][ks], bfr[ni],
                            ks == 0 ? (f32x4){0.f, 0.f, 0.f, 0.f} : accP[mi][ni],
                            0, 0, 0);
            }
            __builtin_amdgcn_s_setprio(0);

            // ---- fold accP -> accO with per-row scale ----
            const int jj = MODE ? (pp * 2 + wn) : pp;
            const float* scp = sc + jj * 256 + wm * 64 + lg * 4;
#pragma unroll
            for (int mi = 0; mi < 4; ++mi) {
                f32x4 sv = *(const f32x4*)(scp + mi * 16);
#pragma unroll
                for (int ni = 0; ni < 4; ++ni)
                    accO[mi][ni] += sv * accP[mi][ni];
            }
        }
    }

    // ---- epilogue: atomic accumulate ----
#pragma unroll
    for (int mi = 0; mi < 4; ++mi)
#pragma unroll
        for (int ni = 0; ni < 4; ++ni)
#pragma unroll
            for (int r = 0; r < 4; ++r) {
                int row = m0 + wm * 64 + mi * 16 + lg * 4 + r;
                int col = MODE ? (ni * 16 + lr)
                               : (cw * 128 + wn * 64 + ni * 16 + lr);
                atomicAdd(outAcc + (size_t)row * OUTW + col, accO[mi][ni][r]);
            }
}

extern "C" void kernel_launch(void* const* d_in, const int* in_sizes, int n_in,
                              void* d_out, int out_size, void* d_ws, size_t ws_size,
                              hipStream_t stream) {
    const float* x     = (const float*)d_in[0];
    const float* W_in  = (const float*)d_in[1];
    const float* b_in  = (const float*)d_in[2];
    const float* W_out = (const float*)d_in[3];
    const float* b_out = (const float*)d_in[4];
    float* out = (float*)d_out;

    char* ws = (char*)d_ws;
    unsigned short* hb = (unsigned short*)ws;            // 2 MB  h bf16
    float* ypre        = (float*)(ws + (2u << 20));      // 4 MB
    float* yv          = (float*)(ws + (6u << 20));      // 4 MB  yv = elu(ypre)
    unsigned short* Wb = (unsigned short*)(ws + (10u << 20));  // 68.2 MB bf16 W_out

    k_h<<<(B_N * 512) / 256, 256, 0, stream>>>(x, W_in, b_in, hb);
    k_conv<<<((size_t)NROWS_PAD * KDIM / 8) / 256, 256, 0, stream>>>(W_out, Wb);

    // ypre := bias terms (l_in_b bias + real-weighted l_in_w biases)
    k_init_ypre<<<(B_N * 512) / 256, 256, 0, stream>>>(x, b_out, ypre);

    // Stage 2: ypre += sum_i real_i * (h @ W_i^T)
    k_pgemm<0><<<256, 512, 0, stream>>>(hb, Wb, x, ypre);

    // yv := elu(ypre)
    k_y<<<(B_N * 512) / 256, 256, 0, stream>>>(ypre, yv);

    // out := bias terms (l_out_b bias + yv-weighted l_out_w biases)
    k_init_out<<<(B_N * 64) / 256, 256, 0, stream>>>(yv, b_out, out);

    // Stage 3: out += sum_h' yv_h' * (h @ W2_h'^T)
    k_pgemm<1><<<256, 512, 0, stream>>>(hb, Wb, yv, out);
}